// Round 5
// baseline (123.177 us; speedup 1.0000x reference)
//
#include <hip/hip_runtime.h>
#include <math.h>
#include <float.h>

#define D_DIM 768
#define K_C   256
#define KC    32
#define NCH   24
#define BMR   128
#define MAXFIX 32768
#define MARGIN 1e-3f

typedef __attribute__((ext_vector_type(8))) short s16x8;
typedef __attribute__((ext_vector_type(4))) float f32x4;

__device__ inline unsigned short f2bf(float x) {      // RNE f32 -> bf16 bits
    unsigned u = __float_as_uint(x);
    unsigned r = 0x7FFFu + ((u >> 16) & 1u);
    return (unsigned short)((u + r) >> 16);
}
__device__ inline float bf2f(unsigned short h) {
    return __uint_as_float(((unsigned)h) << 16);
}
__device__ inline unsigned pk_trunc(float a, float b) { // 2 f32 -> 2 bf16 (trunc)
    return (__float_as_uint(a) >> 16) | (__float_as_uint(b) & 0xFFFF0000u);
}
__device__ inline float hi_of(float x) {                // bf2f(trunc(x))
    return __uint_as_float(__float_as_uint(x) & 0xFFFF0000u);
}
// swizzled elem offset into a [rows][32]-short tile; 16B granule slot 0..3
__device__ inline int swz(int row, int slot) {
    return row*32 + (((slot ^ (row >> 1)) & 3) << 3);
}
__device__ inline void gl_lds16(const void* g, void* l) {
    __builtin_amdgcn_global_load_lds(
        (const __attribute__((address_space(1))) void*)g,
        (__attribute__((address_space(3))) void*)l, 16, 0, 0);
}

// ---------------- c2 in f64, zero fixup counter ----------------
__global__ __launch_bounds__(256) void kc2(const float* __restrict__ C,
    float* __restrict__ c2f, int* __restrict__ fix_cnt)
{
    const int k = blockIdx.x;
    const int t = threadIdx.x;
    __shared__ double red[4];
    double s = 0.0;
    for (int d = t; d < D_DIM; d += 256) {
        double v = (double)C[(size_t)k*D_DIM + d];
        s += v*v;
    }
#pragma unroll
    for (int m = 1; m < 64; m <<= 1) s += __shfl_xor(s, m, 64);
    if ((t & 63) == 0) red[t >> 6] = s;
    __syncthreads();
    if (t == 0) {
        c2f[k] = (float)(red[0] + red[1] + red[2] + red[3]);
        if (k == 0) *fix_cnt = 0;
    }
}

// ---------------- bake C into per-chunk swizzled LDS images ----------------
// image for chunk ch (32 KB): [hi: 8192 shorts swizzled][lo: 8192 shorts]
__global__ __launch_bounds__(256) void kimg(const float* __restrict__ C,
                                            short* __restrict__ Cws)
{
    const int ch = blockIdx.x;          // 0..23
    const int r  = threadIdx.x;         // centroid
    const float* src = C + (size_t)r*D_DIM + ch*KC;
    short* hi = Cws + (size_t)ch*16384;
    short* lo = hi + 8192;
#pragma unroll
    for (int g = 0; g < 4; ++g) {
        int off = swz(r, g);
#pragma unroll
        for (int e = 0; e < 8; ++e) {
            float x = src[g*8 + e];
            unsigned short h = f2bf(x);
            unsigned short l = f2bf(x - bf2f(h));
            hi[off + e] = (short)h;
            lo[off + e] = (short)l;
        }
    }
}

// ---------------- main fused MFMA kernel: 128 rows x 256 cols, 4 waves ----------------
__global__ __launch_bounds__(256, 2) void kdist(const float* __restrict__ E,
    const short* __restrict__ Cws, const float* __restrict__ c2f,
    float* __restrict__ labels, float* __restrict__ partials,
    int* __restrict__ fix_cnt, int* __restrict__ fix_list)
{
    __shared__ __align__(16) char ldsbuf[81920];
    short* EhiL = (short*)ldsbuf;                 // [128][32] swizzled, 8 KB
    short* EloL = EhiL + BMR*KC;                  // 8 KB
    char*  Cb0  = (char*)(EloL + BMR*KC);         // 32 KB (hi 8192 sh, lo 8192 sh)
    char*  Cb1  = Cb0 + 32768;                    // 32 KB
    // epilogue overlay (on E region, valid after final loop barrier)
    float*  e2s   = (float*)ldsbuf;               // [128]
    float*  spart = (float*)(ldsbuf + 512);       // [2][256][3]
    float4* topb  = (float4*)(ldsbuf + 512 + 6144); // [2][128]

    const int t    = threadIdx.x;
    const int lane = t & 63;
    const int w    = t >> 6;                      // 0..3
    const int wm   = w >> 1, wn = w & 1;          // row-half / col-half
    const int c4   = lane & 15, sgr = lane >> 4;
    const int R0   = blockIdx.x * BMR;

    f32x4 acc[4][8];
#pragma unroll
    for (int m = 0; m < 4; ++m)
#pragma unroll
        for (int n = 0; n < 8; ++n) acc[m][n] = (f32x4){0.f,0.f,0.f,0.f};

    // E staging: 2 threads/row, 16 f32 each
    const int erow = t >> 1, ehalf = t & 1;
    const float* Ep = E + (size_t)(R0 + erow)*D_DIM + ehalf*16;
    const int eg0 = ehalf*2;
    short* ehd0 = &EhiL[swz(erow, eg0)];
    short* ehd1 = &EhiL[swz(erow, eg0+1)];
    short* eld0 = &EloL[swz(erow, eg0)];
    short* eld1 = &EloL[swz(erow, eg0+1)];

    float e2p = 0.f;
    float4 q0, q1, q2, q3;

#define ECONV_WRITE() do {                                              \
        e2p = fmaf(q0.x,q0.x,e2p); e2p = fmaf(q0.y,q0.y,e2p);           \
        e2p = fmaf(q0.z,q0.z,e2p); e2p = fmaf(q0.w,q0.w,e2p);           \
        e2p = fmaf(q1.x,q1.x,e2p); e2p = fmaf(q1.y,q1.y,e2p);           \
        e2p = fmaf(q1.z,q1.z,e2p); e2p = fmaf(q1.w,q1.w,e2p);           \
        e2p = fmaf(q2.x,q2.x,e2p); e2p = fmaf(q2.y,q2.y,e2p);           \
        e2p = fmaf(q2.z,q2.z,e2p); e2p = fmaf(q2.w,q2.w,e2p);           \
        e2p = fmaf(q3.x,q3.x,e2p); e2p = fmaf(q3.y,q3.y,e2p);           \
        e2p = fmaf(q3.z,q3.z,e2p); e2p = fmaf(q3.w,q3.w,e2p);           \
        uint4 H0, L0, H1, L1;                                           \
        H0.x = pk_trunc(q0.x,q0.y); H0.y = pk_trunc(q0.z,q0.w);         \
        H0.z = pk_trunc(q1.x,q1.y); H0.w = pk_trunc(q1.z,q1.w);         \
        L0.x = pk_trunc(q0.x-hi_of(q0.x), q0.y-hi_of(q0.y));            \
        L0.y = pk_trunc(q0.z-hi_of(q0.z), q0.w-hi_of(q0.w));            \
        L0.z = pk_trunc(q1.x-hi_of(q1.x), q1.y-hi_of(q1.y));            \
        L0.w = pk_trunc(q1.z-hi_of(q1.z), q1.w-hi_of(q1.w));            \
        H1.x = pk_trunc(q2.x,q2.y); H1.y = pk_trunc(q2.z,q2.w);         \
        H1.z = pk_trunc(q3.x,q3.y); H1.w = pk_trunc(q3.z,q3.w);         \
        L1.x = pk_trunc(q2.x-hi_of(q2.x), q2.y-hi_of(q2.y));            \
        L1.y = pk_trunc(q2.z-hi_of(q2.z), q2.w-hi_of(q2.w));            \
        L1.z = pk_trunc(q3.x-hi_of(q3.x), q3.y-hi_of(q3.y));            \
        L1.w = pk_trunc(q3.z-hi_of(q3.z), q3.w-hi_of(q3.w));            \
        *reinterpret_cast<uint4*>(ehd0) = H0;                           \
        *reinterpret_cast<uint4*>(ehd1) = H1;                           \
        *reinterpret_cast<uint4*>(eld0) = L0;                           \
        *reinterpret_cast<uint4*>(eld1) = L1;                           \
    } while (0)

    // ---- prologue: chunk 0 ----
    {
        q0 = *reinterpret_cast<const float4*>(Ep);
        q1 = *reinterpret_cast<const float4*>(Ep + 4);
        q2 = *reinterpret_cast<const float4*>(Ep + 8);
        q3 = *reinterpret_cast<const float4*>(Ep + 12);
        const char* gsrc = (const char*)Cws + (size_t)(w*8)*1024 + lane*16;
#pragma unroll
        for (int j = 0; j < 8; ++j)
            gl_lds16(gsrc + j*1024, Cb0 + (size_t)(w*8 + j)*1024);
        ECONV_WRITE();
    }
    __syncthreads();   // drains vmcnt -> C0 + E0 ready

    for (int ch = 0; ch < NCH; ++ch) {
        const bool pre = (ch + 1 < NCH);
        char* curC = (ch & 1) ? Cb1 : Cb0;
        char* nxtC = (ch & 1) ? Cb0 : Cb1;
        if (pre) {
            const float* ep = Ep + (ch+1)*KC;
            q0 = *reinterpret_cast<const float4*>(ep);
            q1 = *reinterpret_cast<const float4*>(ep + 4);
            q2 = *reinterpret_cast<const float4*>(ep + 8);
            q3 = *reinterpret_cast<const float4*>(ep + 12);
            const char* gsrc = (const char*)Cws + (size_t)(ch+1)*32768
                               + (size_t)(w*8)*1024 + lane*16;
#pragma unroll
            for (int j = 0; j < 8; ++j)
                gl_lds16(gsrc + j*1024, nxtC + (size_t)(w*8 + j)*1024);
        }
        // ---- MFMA: acc += (Ehi+Elo)*Chi + Ehi*Clo ----
        const short* Chi = (const short*)curC;
        const short* Clo = Chi + 8192;
        s16x8 ah[4], al[4];
#pragma unroll
        for (int m = 0; m < 4; ++m) {
            int o = swz(wm*64 + m*16 + c4, sgr);
            ah[m] = *reinterpret_cast<const s16x8*>(&EhiL[o]);
            al[m] = *reinterpret_cast<const s16x8*>(&EloL[o]);
        }
#pragma unroll
        for (int n = 0; n < 8; ++n) {
            int o = swz(wn*128 + n*16 + c4, sgr);
            s16x8 bh = *reinterpret_cast<const s16x8*>(&Chi[o]);
            s16x8 bl = *reinterpret_cast<const s16x8*>(&Clo[o]);
#pragma unroll
            for (int m = 0; m < 4; ++m)
                acc[m][n] = __builtin_amdgcn_mfma_f32_16x16x32_bf16(ah[m], bh, acc[m][n], 0, 0, 0);
#pragma unroll
            for (int m = 0; m < 4; ++m)
                acc[m][n] = __builtin_amdgcn_mfma_f32_16x16x32_bf16(al[m], bh, acc[m][n], 0, 0, 0);
#pragma unroll
            for (int m = 0; m < 4; ++m)
                acc[m][n] = __builtin_amdgcn_mfma_f32_16x16x32_bf16(ah[m], bl, acc[m][n], 0, 0, 0);
        }
        __syncthreads();           // readers done with E LDS; prefetch loads drained
        if (pre) ECONV_WRITE();
        __syncthreads();           // E(ch+1) visible; C(ch+1) landed pre-barrier
    }

    // ---- e2 per row (2 threads/row) ----
    {
        float o = __shfl_xor(e2p, 1, 64);
        if ((t & 1) == 0) e2s[t >> 1] = e2p + o;
    }
    __syncthreads();

    float e2r[4][4];
#pragma unroll
    for (int m = 0; m < 4; ++m)
#pragma unroll
        for (int g = 0; g < 4; ++g)
            e2r[m][g] = e2s[wm*64 + m*16 + sgr*4 + g];
    float c2v[8];
#pragma unroll
    for (int n = 0; n < 8; ++n) c2v[n] = c2f[wn*128 + n*16 + c4];

    // dot -> dist (C/D: col=lane&15 -> centroid, row=(lane>>4)*4+g -> E row)
#pragma unroll
    for (int m = 0; m < 4; ++m)
#pragma unroll
        for (int n = 0; n < 8; ++n) {
            f32x4 v = acc[m][n];
#pragma unroll
            for (int g = 0; g < 4; ++g) {
                float d2 = fmaf(-2.f, v[g], e2r[m][g] + c2v[n]);
                v[g] = sqrtf(fmaxf(d2, 0.f));
            }
            acc[m][n] = v;
        }

    // ---- top-2 per row over this wave's 128 cols ----
#pragma unroll
    for (int m = 0; m < 4; ++m)
#pragma unroll
        for (int g = 0; g < 4; ++g) {
            float v1 = FLT_MAX, v2 = FLT_MAX;
            int i1 = 0x7fffffff, i2 = 0x7fffffff;
#pragma unroll
            for (int n = 0; n < 8; ++n) {
                float d = acc[m][n][g];
                int idx = wn*128 + n*16 + c4;
                if (d < v1)      { v2 = v1; i2 = i1; v1 = d; i1 = idx; }
                else if (d < v2) { v2 = d; i2 = idx; }
            }
#pragma unroll
            for (int msk = 1; msk < 16; msk <<= 1) {
                float b1 = __shfl_xor(v1, msk, 64); int bi1 = __shfl_xor(i1, msk, 64);
                float b2 = __shfl_xor(v2, msk, 64); int bi2 = __shfl_xor(i2, msk, 64);
                bool afirst = (v1 < b1) || (v1 == b1 && i1 < bi1);
                float n1, n2; int ni1, ni2;
                if (afirst) {
                    n1 = v1; ni1 = i1;
                    bool s = (v2 < b1) || (v2 == b1 && i2 < bi1);
                    n2 = s ? v2 : b1; ni2 = s ? i2 : bi1;
                } else {
                    n1 = b1; ni1 = bi1;
                    bool s = (b2 < v1) || (b2 == v1 && bi2 < i1);
                    n2 = s ? b2 : v1; ni2 = s ? bi2 : i1;
                }
                v1 = n1; i1 = ni1; v2 = n2; i2 = ni2;
            }
            if (c4 == 0) {
                float4 r; r.x = v1; r.y = (float)i1; r.z = v2; r.w = (float)i2;
                topb[(size_t)wn*BMR + wm*64 + m*16 + sgr*4 + g] = r;
            }
        }

    // ---- per-centroid softmin partials over this wave's 64 rows ----
#pragma unroll
    for (int n = 0; n < 8; ++n) {
        float m0 = FLT_MAX;
#pragma unroll
        for (int m = 0; m < 4; ++m)
#pragma unroll
            for (int g = 0; g < 4; ++g) m0 = fminf(m0, acc[m][n][g]);
        float s1 = 0.f, s2 = 0.f;
#pragma unroll
        for (int m = 0; m < 4; ++m)
#pragma unroll
            for (int g = 0; g < 4; ++g) {
                float d = acc[m][n][g];
                float e = expf(m0 - d);
                s1 += e; s2 = fmaf(d, e, s2);
            }
#pragma unroll
        for (int msk = 16; msk < 64; msk <<= 1) {
            float om = __shfl_xor(m0, msk, 64);
            float oa = __shfl_xor(s1, msk, 64);
            float ob = __shfl_xor(s2, msk, 64);
            float Mn = fminf(m0, om);
            float sa = expf(Mn - m0), sb = expf(Mn - om);
            s1 = s1*sa + oa*sb;
            s2 = s2*sa + ob*sb;
            m0 = Mn;
        }
        if (lane < 16) {
            int cc = wn*128 + n*16 + c4;
            float* p = &spart[((size_t)wm*K_C + cc)*3];
            p[0] = m0; p[1] = s1; p[2] = s2;
        }
    }
    __syncthreads();

    if (t < BMR) {
        float4 a = topb[t];                 // wn=0: cols 0..127
        float4 b = topb[(size_t)BMR + t];   // wn=1: cols 128..255
        float v1, v2; int i1, i2;
        if (a.x <= b.x) {
            v1 = a.x; i1 = (int)a.y;
            bool s = (a.z <= b.x);
            v2 = s ? a.z : b.x; i2 = s ? (int)a.w : (int)b.y;
        } else {
            v1 = b.x; i1 = (int)b.y;
            bool s = (a.x <= b.z);
            v2 = s ? a.x : b.z; i2 = s ? (int)a.y : (int)b.w;
        }
        int row = R0 + t;
        labels[row] = (float)i1;
        if (v2 - v1 < MARGIN) {
            int slot = atomicAdd(fix_cnt, 1);
            if (slot < MAXFIX) {
                fix_list[slot*3+0] = row;
                fix_list[slot*3+1] = i1;
                fix_list[slot*3+2] = i2;
            }
        }
    }
    if (t < K_C) {
        const float* p0 = &spart[(size_t)t*3];
        const float* p1 = &spart[((size_t)K_C + t)*3];
        float M = p0[0], A = p0[1], Bv = p0[2];
        float om = p1[0], oa = p1[1], ob = p1[2];
        float Mn = fminf(M, om);
        float sa = expf(Mn - M), sb = expf(Mn - om);
        A = A*sa + oa*sb; Bv = Bv*sa + ob*sb;
        float* p = &partials[((size_t)blockIdx.x*K_C + t)*3];
        p[0] = Mn; p[1] = A; p[2] = Bv;
    }
#undef ECONV_WRITE
}

// ---------------- f64 exact compare of flagged top-2 ----------------
__global__ __launch_bounds__(256) void krefB(const float* __restrict__ E,
    const float* __restrict__ C, const int* __restrict__ fix_cnt,
    const int* __restrict__ fix_list, float* __restrict__ labels)
{
    int cnt = *fix_cnt; if (cnt > MAXFIX) cnt = MAXFIX;
    int lane = threadIdx.x & 63;
    int wv = (int)((blockIdx.x * blockDim.x + threadIdx.x) >> 6);
    const int NW = (gridDim.x * blockDim.x) >> 6;
    for (int e = wv; e < cnt; e += NW) {
        int row = fix_list[e*3+0], k1 = fix_list[e*3+1], k2 = fix_list[e*3+2];
        double d1 = 0, d2 = 0, q1 = 0, q2 = 0;
        for (int d = lane; d < D_DIM; d += 64) {
            double ed = (double)E[(size_t)row*D_DIM + d];
            double ca = (double)C[(size_t)k1*D_DIM + d];
            double cb = (double)C[(size_t)k2*D_DIM + d];
            d1 += ed*ca; q1 += ca*ca;
            d2 += ed*cb; q2 += cb*cb;
        }
#pragma unroll
        for (int msk = 32; msk; msk >>= 1) {
            d1 += __shfl_down(d1, msk, 64);
            d2 += __shfl_down(d2, msk, 64);
            q1 += __shfl_down(q1, msk, 64);
            q2 += __shfl_down(q2, msk, 64);
        }
        if (lane == 0) {
            double val1 = q1 - 2.0*d1, val2 = q2 - 2.0*d2;   // e2 cancels
            int lab = (val2 < val1 || (val2 == val1 && k2 < k1)) ? k2 : k1;
            labels[row] = (float)lab;
        }
    }
}

// ---------------- per-centroid global combine ----------------
__global__ __launch_bounds__(256) void kcol(const float* __restrict__ partials,
                                            float* __restrict__ colloss, int NB)
{
    __shared__ float Wm[4], Wa[4], Wb[4];
    const int c = blockIdx.x;
    const int t = threadIdx.x;
    float M = FLT_MAX, A = 0.f, Bv = 0.f;
    for (int b = t; b < NB; b += 256) {
        const float* p = &partials[((size_t)b*K_C + c)*3];
        float om = p[0], oa = p[1], ob = p[2];
        float Mn = fminf(M, om);
        float sa = expf(Mn - M), sb = expf(Mn - om);
        A = A*sa + oa*sb; Bv = Bv*sa + ob*sb; M = Mn;
    }
    for (int msk = 1; msk < 64; msk <<= 1) {
        float om = __shfl_xor(M, msk, 64);
        float oa = __shfl_xor(A, msk, 64);
        float ob = __shfl_xor(Bv, msk, 64);
        float Mn = fminf(M, om);
        float sa = expf(Mn - M), sb = expf(Mn - om);
        A = A*sa + oa*sb; Bv = Bv*sa + ob*sb; M = Mn;
    }
    int lane = t & 63, wv = t >> 6;
    if (lane == 0) { Wm[wv] = M; Wa[wv] = A; Wb[wv] = Bv; }
    __syncthreads();
    if (t == 0) {
#pragma unroll
        for (int i = 1; i < 4; ++i) {
            float om = Wm[i], oa = Wa[i], ob = Wb[i];
            float Mn = fminf(M, om);
            float sa = expf(Mn - M), sb = expf(Mn - om);
            A = A*sa + oa*sb; Bv = Bv*sa + ob*sb; M = Mn;
        }
        colloss[c] = Bv / A;
    }
}

// ---------------- final mean over centroids ----------------
__global__ __launch_bounds__(256) void kfinal(const float* __restrict__ colloss,
                                              float* __restrict__ out)
{
    __shared__ float Ws[4];
    int t = threadIdx.x;
    float v = colloss[t];
    for (int msk = 1; msk < 64; msk <<= 1) v += __shfl_xor(v, msk, 64);
    if ((t & 63) == 0) Ws[t >> 6] = v;
    __syncthreads();
    if (t == 0) out[0] = (Ws[0] + Ws[1] + Ws[2] + Ws[3]) / 256.0f;
}

extern "C" void kernel_launch(void* const* d_in, const int* in_sizes, int n_in,
                              void* d_out, int out_size, void* d_ws, size_t ws_size,
                              hipStream_t stream)
{
    const float* E = (const float*)d_in[0];
    const float* C = (const float*)d_in[1];
    float* out = (float*)d_out;

    const int Bn = in_sizes[0] / D_DIM;      // 65536
    const int NB = Bn / BMR;                 // 512

    char* ws = (char*)d_ws;
    float* c2f      = (float*)ws;                                  // 1 KB
    int*   fix_cnt  = (int*)(ws + 1024);
    int*   fix_list = (int*)(ws + 1088);                           // MAXFIX*12
    short* Cws      = (short*)(ws + 1088 + MAXFIX*12);             // 768 KB
    float* partials = (float*)((char*)Cws + (size_t)NCH*32768);    // NB*256*3*4
    float* colloss  = partials + (size_t)NB*K_C*3;
    float* labels   = out + 1;

    kc2   <<<K_C, 256, 0, stream>>>(C, c2f, fix_cnt);
    kimg  <<<NCH, 256, 0, stream>>>(C, Cws);
    kdist <<<NB,  256, 0, stream>>>(E, Cws, c2f, labels, partials,
                                    fix_cnt, fix_list);
    krefB <<<256, 256, 0, stream>>>(E, C, fix_cnt, fix_list, labels);
    kcol  <<<K_C, 256, 0, stream>>>(partials, colloss, NB);
    kfinal<<<1,   256, 0, stream>>>(colloss, out);
}